// Round 4
// baseline (413.190 us; speedup 1.0000x reference)
//
#include <hip/hip_runtime.h>
#include <math.h>

#define NXY    192
#define CELLS  (NXY*NXY)
#define NBATCH 4
#define NSTEPS 256
#define TCH    32                 // steps per chunk (= halo width)
#define NCHUNK (NSTEPS/TCH)       // 8
#define TPB    512                // 8 waves
#define RPL    12                 // rows per lane (96 rows / 8 waves)
#define NBLKS  (NBATCH*18)        // 72 persistent blocks (<=256 CUs, co-resident)
// in-tile 128 wide x 96 tall; out-tile 64 wide x 32 tall; 6x3 tiles per batch

// workspace layout (float offsets)
#define K3_OFF (16*CELLS)
#define A1_OFF (K3_OFF + CELLS)
#define I_OFF  (A1_OFF + CELLS)
#define C_OFF  (I_OFF + 16)       // 16 int counters, stride 32 ints (128B)

__device__ __forceinline__ float dpp_up1(float v) {
    int r = __builtin_amdgcn_update_dpp(0, __builtin_bit_cast(int, v),
                                        0x138, 0xf, 0xf, true); // wave_shr:1
    return __builtin_bit_cast(float, r);
}
__device__ __forceinline__ float dpp_dn1(float v) {
    int r = __builtin_amdgcn_update_dpp(0, __builtin_bit_cast(int, v),
                                        0x130, 0xf, 0xf, true); // wave_shl:1
    return __builtin_bit_cast(float, r);
}

__device__ __forceinline__ float pml_prof(int i) {
    int t;
    if (i <= 20)            t = 20 - i;
    else if (i >= NXY - 21) t = i - (NXY - 21);
    else                    return 0.0f;
    float u  = (float)t * 0.05f;
    float u2 = u * u;
    return 3.0f * u2 * u2;
}

__global__ void init_k(float* __restrict__ ws) {
    int t = threadIdx.x;
    int* cnt = (int*)(ws + C_OFF);
    if (t < 16 * 32) cnt[t] = 0;
    if (t < 16) ws[I_OFF + t] = 0.0f;
}

// device-scope grid barrier; each sync id uses a fresh counter (no reset race)
__device__ __forceinline__ void gsync(int* cnt, int id) {
    __syncthreads();
    if (threadIdx.x == 0) {
        __threadfence();   // release our global writes
        __hip_atomic_fetch_add(&cnt[id * 32], 1, __ATOMIC_ACQ_REL,
                               __HIP_MEMORY_SCOPE_AGENT);
        while (__hip_atomic_load(&cnt[id * 32], __ATOMIC_ACQUIRE,
                                 __HIP_MEMORY_SCOPE_AGENT) < NBLKS)
            __builtin_amdgcn_s_sleep(1);
    }
    __syncthreads();
    __threadfence();       // acquire: invalidate stale L1 lines for this CU
}

__global__ __launch_bounds__(TPB, 1)
void wave_k(const float* __restrict__ x, const float* __restrict__ rho,
            float* __restrict__ ws, float* __restrict__ out) {
    int* cnt = (int*)(ws + C_OFF);
    int blk = blockIdx.x;
    int t   = threadIdx.x;

    // ---- setup phase: zero parity-0 fields + compute coefficients ----
    {
        int gid = blk * TPB + t, gstride = NBLKS * TPB;
        for (int k = gid; k < 8 * CELLS; k += gstride) ws[k] = 0.0f;
        const float IH2 = (float)(1.0 / (2.01 * 2.01));
        for (int k = gid; k < CELLS; k += gstride) {
            int i = k / NXY, j = k % NXY;
            float r0 = rho[k];
            float ru = (i > 0)       ? rho[k - NXY] : 0.0f;
            float rd = (i < NXY - 1) ? rho[k + NXY] : 0.0f;
            float rl = (j > 0)       ? rho[k - 1]   : 0.0f;
            float rr2 = (j < NXY - 1) ? rho[k + 1]  : 0.0f;
            float lpf = 0.5f * r0 + 0.125f * ((ru + rd) + (rl + rr2));
            float p   = 0.5f * (1.0f + tanhf(100.0f * (lpf - 0.5f)));
            float c   = 1.0f - 0.1f * p;
            float c2h = c * c * IH2;
            float bx = pml_prof(i), by = pml_prof(j);
            float bb = sqrtf(bx * bx + by * by);
            float a1 = 1.0f / (1.0f + 0.5f * bb);
            ws[K3_OFF + k] = a1 * c2h;     // K
            ws[A1_OFF + k] = a1;           // A1
        }
    }

    // ---- per-block geometry ----
    int b  = blk / 18;
    int rr = blk % 18;
    int bi = rr / 3, bj = rr % 3;
    int I0 = 32 * bi - 32;
    int J0 = 64 * bj - 32;
    int w  = t >> 6;                  // wave 0..7, owns rows [12w, 12w+12)
    int l  = t & 63;                  // lane, owns cols 2l, 2l+1 (local)
    int row0 = I0 + RPL * w;
    int gj   = J0 + 2 * l;

    __shared__ float2 hb[2][2][10][64];   // [parity][top/bot][slot][lane]
    __shared__ float xs_l[TCH];
    for (int k = t; k < 2 * 2 * 10 * 64; k += TPB)
        ((float2*)hb)[k] = make_float2(0.f, 0.f);   // edge slots stay 0 forever

    gsync(cnt, 0);   // coefficients + zeroed fields visible; hb zeros + barrier

    // ---- persistent per-lane coefficients (live in regs all 256 steps) ----
    const float* kg = ws + K3_OFF;
    const float* ag = ws + A1_OFF;
    float Qa[RPL][2], Ka[RPL][2];
    bool cok = (gj >= 0 && gj < NXY);
#pragma unroll
    for (int r = 0; r < RPL; r++) {
        int gi = row0 + r;
        bool ok = cok && gi >= 0 && gi < NXY;
        float2 kv = {0.f,0.f}, av = {0.f,0.f};
        if (ok) {
            int idx = gi * NXY + gj;
            kv = *(const float2*)(kg + idx);
            av = *(const float2*)(ag + idx);
        }
        Ka[r][0] = kv.x; Ka[r][1] = kv.y;
        // out-of-domain: K=0,Q=0 -> yn = c = 0 forever
        Qa[r][0] = ok ? (1.f - 2.f * av.x) : 0.f;
        Qa[r][1] = ok ? (1.f - 2.f * av.y) : 0.f;
    }

    // source (40,96): always lands on an even (c0) column for all bj
    int sr = 40 - I0, sc = 96 - J0;
    bool wave_src = (sc >= 0 && sc < 128) && (sr >= RPL * w) && (sr < RPL * w + RPL);
    int src_rl = sr - RPL * w;
    float srcm = (2 * l == sc) ? 1.f : 0.f;

    // probe: row 160, col 48+48*bj, owned when bi==5 (also even column)
    bool blk_prb = (bi == 5);
    int pcol = 48 + 48 * bj;
    int pr = 160 - I0;
    bool wave_prb = blk_prb && (pr >= RPL * w) && (pr < RPL * w + RPL);
    int prb_rl = pr - RPL * w;
    float prbm = (2 * l == (pcol - J0)) ? 1.f : 0.f;
    float pacc = 0.f;   // accumulates across ALL 8 chunks in-register

    float yc[RPL][2], yp[RPL][2];
    float2 uph, dnh;

// per-row update: yn = c + Q*(p-c) + K*(S-4c), plus src/probe on c0
#define ROWC(CUR, PRV, rr_, u0, u1, d0, d1, Y0, Y1) do {                       \
    float c0 = CUR[rr_][0], c1 = CUR[rr_][1];                                  \
    float lf0 = dpp_up1(c1);                                                   \
    float rt1 = dpp_dn1(c0);                                                   \
    float s0 = ((u0) + (d0)) + (lf0 + c1);                                     \
    float s1 = ((u1) + (d1)) + (c0 + rt1);                                     \
    Y0 = c0 + Qa[rr_][0] * (PRV[rr_][0] - c0) + Ka[rr_][0] * (s0 - 4.f * c0);  \
    Y1 = c1 + Qa[rr_][1] * (PRV[rr_][1] - c1) + Ka[rr_][1] * (s1 - 4.f * c1);  \
    if (wave_src && (rr_) == src_rl) Y0 += srcm * xsv;                         \
    if (wave_prb && (rr_) == prb_rl) { float tq = prbm * Y0; pacc += tq * Y0; } \
} while (0)

// pipelined step: boundary rows first -> LDS write early; interior hides the
// write; barrier; halo read issued here, first used NEXT step (full-step slack)
#define STEP(CUR, PRV, PH, SIDX) do {                                          \
    float xsv = xs_l[SIDX];                                                    \
    float t00, t01, tB0, tB1;                                                  \
    ROWC(CUR, PRV, 0,  uph.x, uph.y, CUR[1][0],  CUR[1][1],  t00, t01);        \
    ROWC(CUR, PRV, 11, CUR[10][0], CUR[10][1], dnh.x, dnh.y, tB0, tB1);        \
    hb[PH][0][w + 1][l] = make_float2(t00, t01);                               \
    hb[PH][1][w + 1][l] = make_float2(tB0, tB1);                               \
    PRV[0][0] = t00; PRV[0][1] = t01;                                          \
    PRV[11][0] = tB0; PRV[11][1] = tB1;                                        \
    _Pragma("unroll")                                                          \
    for (int r = 1; r <= 10; r++) {                                            \
        float y0, y1;                                                          \
        ROWC(CUR, PRV, r, CUR[r-1][0], CUR[r-1][1], CUR[r+1][0], CUR[r+1][1],  \
             y0, y1);                                                          \
        PRV[r][0] = y0; PRV[r][1] = y1;                                        \
    }                                                                          \
    __syncthreads();                                                           \
    uph = hb[PH][1][w][l];                                                     \
    dnh = hb[PH][0][w + 2][l];                                                 \
} while (0)

#pragma unroll 1
    for (int chunk = 0; chunk < NCHUNK; chunk++) {
        int pin = chunk & 1, pout = pin ^ 1;
        const float* curg  = ws + ((pin  * 2 + 0) * NBATCH + b) * CELLS;
        const float* prvg  = ws + ((pin  * 2 + 1) * NBATCH + b) * CELLS;
        float*       ncurg = ws + ((pout * 2 + 0) * NBATCH + b) * CELLS;
        float*       nprvg = ws + ((pout * 2 + 1) * NBATCH + b) * CELLS;

        if (t < TCH) xs_l[t] = x[b * NSTEPS + chunk * TCH + t];

        // load in-tile state
#pragma unroll
        for (int r = 0; r < RPL; r++) {
            int gi = row0 + r;
            bool ok = cok && gi >= 0 && gi < NXY;
            float2 cv = {0.f,0.f}, pv = {0.f,0.f};
            if (ok) {
                int idx = gi * NXY + gj;
                cv = *(const float2*)(curg + idx);
                pv = *(const float2*)(prvg + idx);
            }
            yc[r][0] = cv.x; yc[r][1] = cv.y;
            yp[r][0] = pv.x; yp[r][1] = pv.y;
        }

        // chunk prologue: initial halo exchange (parity 0)
        hb[0][0][w + 1][l] = make_float2(yc[0][0],  yc[0][1]);
        hb[0][1][w + 1][l] = make_float2(yc[11][0], yc[11][1]);
        __syncthreads();
        uph = hb[0][1][w][l];
        dnh = hb[0][0][w + 2][l];

#pragma unroll 1
        for (int s2 = 0; s2 < TCH / 2; s2++) {
            STEP(yc, yp, 1, 2 * s2);        // new cur -> yp, writes hb[1]
            STEP(yp, yc, 0, 2 * s2 + 1);    // new cur -> yc, writes hb[0]
        }
        // yc = y(t_end), yp = y(t_end - 1)

        // store out-tile: rows [32bi,32bi+32), cols [J0+32,J0+96) = lanes 16..47
#pragma unroll
        for (int r = 0; r < RPL; r++) {
            int gi = row0 + r;
            if (gi >= 32 * bi && gi < 32 * bi + 32 && l >= 16 && l < 48) {
                int idx = gi * NXY + gj;
                *(float2*)(ncurg + idx) = make_float2(yc[r][0], yc[r][1]);
                *(float2*)(nprvg + idx) = make_float2(yp[r][0], yp[r][1]);
            }
        }
        gsync(cnt, 1 + chunk);
    }
#undef STEP
#undef ROWC

    // probe owners publish I (unique writer per (b, bj))
    if (wave_prb && prbm == 1.f) ws[I_OFF + b * 3 + bj] = pacc;
    gsync(cnt, 1 + NCHUNK);

    if (blk == 0 && t < 12) {
        const float* I = ws + I_OFF;
        int bb2 = t / 3;
        float s = I[3 * bb2] + I[3 * bb2 + 1] + I[3 * bb2 + 2];
        out[t] = I[t] / s;
    }
}

extern "C" void kernel_launch(void* const* d_in, const int* in_sizes, int n_in,
                              void* d_out, int out_size, void* d_ws, size_t ws_size,
                              hipStream_t stream) {
    const float* x   = (const float*)d_in[0];   // (4,256) fp32
    const float* rho = (const float*)d_in[1];   // (192,192) fp32
    float* ws  = (float*)d_ws;
    float* out = (float*)d_out;

    init_k<<<1, 512, 0, stream>>>(ws);
    wave_k<<<NBLKS, TPB, 0, stream>>>(x, rho, ws, out);
}

// Round 5
// 244.187 us; speedup vs baseline: 1.6921x; 1.6921x over previous
//
#include <hip/hip_runtime.h>
#include <math.h>

#define NXY    192
#define CELLS  (NXY*NXY)
#define NBATCH 4
#define NSTEPS 256
#define TCH    32                 // steps per chunk (= halo width)
#define NCHUNK (NSTEPS/TCH)       // 8
#define TPB    512                // 8 waves
#define RPL    10                 // rows per lane (80 rows / 8 waves)
#define NBLKS  144                // 12 row-tiles x 3 col-tiles x 4 batches
// in-tile 128 wide x 80 tall; out-tile 64 wide x 16 tall

// workspace layout (float offsets)
#define K3_OFF (16*CELLS)
#define A1_OFF (K3_OFF + CELLS)
#define I_OFF  (A1_OFF + CELLS)

typedef float v2f __attribute__((ext_vector_type(2)));

__device__ __forceinline__ float dpp_up1(float v) {
    int r = __builtin_amdgcn_update_dpp(0, __builtin_bit_cast(int, v),
                                        0x138, 0xf, 0xf, true); // wave_shr:1
    return __builtin_bit_cast(float, r);
}
__device__ __forceinline__ float dpp_dn1(float v) {
    int r = __builtin_amdgcn_update_dpp(0, __builtin_bit_cast(int, v),
                                        0x130, 0xf, 0xf, true); // wave_shl:1
    return __builtin_bit_cast(float, r);
}

__device__ __forceinline__ float pml_prof(int i) {
    int t;
    if (i <= 20)            t = 20 - i;
    else if (i >= NXY - 21) t = i - (NXY - 21);
    else                    return 0.0f;
    float u  = (float)t * 0.05f;
    float u2 = u * u;
    return 3.0f * u2 * u2;
}

__global__ void setup_k(const float* __restrict__ rho, float* __restrict__ ws) {
    int idx    = blockIdx.x * blockDim.x + threadIdx.x;
    int stride = gridDim.x * blockDim.x;
    for (int k = idx; k < 8 * CELLS; k += stride) ws[k] = 0.0f;
    const float IH2 = (float)(1.0 / (2.01 * 2.01));
    for (int k = idx; k < CELLS; k += stride) {
        int i = k / NXY, j = k % NXY;
        float r0 = rho[k];
        float ru = (i > 0)       ? rho[k - NXY] : 0.0f;
        float rd = (i < NXY - 1) ? rho[k + NXY] : 0.0f;
        float rl = (j > 0)       ? rho[k - 1]   : 0.0f;
        float rr2 = (j < NXY - 1) ? rho[k + 1]  : 0.0f;
        float lpf = 0.5f * r0 + 0.125f * ((ru + rd) + (rl + rr2));
        float p   = 0.5f * (1.0f + tanhf(100.0f * (lpf - 0.5f)));
        float c   = 1.0f - 0.1f * p;
        float c2h = c * c * IH2;
        float bx = pml_prof(i), by = pml_prof(j);
        float bb = sqrtf(bx * bx + by * by);
        float a1 = 1.0f / (1.0f + 0.5f * bb);
        ws[K3_OFF + k] = a1 * c2h;     // K
        ws[A1_OFF + k] = a1;           // A1 (Q derived at load)
    }
    if (idx < 12) ws[I_OFF + idx] = 0.0f;
}

__global__ __launch_bounds__(TPB, 1)
void chunk_k(const float* __restrict__ x, float* __restrict__ ws, int chunk) {
    int blk = blockIdx.x;
    int b  = blk / 36;                // batch
    int rr = blk % 36;
    int bi = rr / 3, bj = rr % 3;     // 12 row-tiles x 3 col-tiles
    int I0 = 16 * bi - 32;            // in-tile row origin (80 rows)
    int J0 = 64 * bj - 32;            // in-tile col origin (128 cols)
    int t  = threadIdx.x;
    int w  = t >> 6;                  // wave 0..7, owns rows [10w, 10w+10)
    int l  = t & 63;                  // lane, owns cols 2l, 2l+1 (local)
    int row0 = I0 + RPL * w;
    int gj   = J0 + 2 * l;

    __shared__ v2f hb[2][2][10][64];  // [parity][top/bot][slot 0..9][lane]
    __shared__ float xs_l[TCH];
    for (int k = t; k < 2 * 2 * 10 * 64; k += TPB)
        ((v2f*)hb)[k] = (v2f){0.f, 0.f};        // edge slots stay 0 forever
    if (t < TCH) xs_l[t] = x[b * NSTEPS + chunk * TCH + t];

    const float* kg = ws + K3_OFF;
    const float* ag = ws + A1_OFF;
    int pin = chunk & 1, pout = pin ^ 1;
    const float* curg  = ws + ((pin  * 2 + 0) * NBATCH + b) * CELLS;
    const float* prvg  = ws + ((pin  * 2 + 1) * NBATCH + b) * CELLS;
    float*       ncurg = ws + ((pout * 2 + 0) * NBATCH + b) * CELLS;
    float*       nprvg = ws + ((pout * 2 + 1) * NBATCH + b) * CELLS;

    // per-lane state: 4 v2f arrays x 10 rows = 80 VGPRs
    v2f yc[RPL], yp[RPL], Qa[RPL], Ka[RPL];
    bool cok = (gj >= 0 && gj < NXY);
#pragma unroll
    for (int r = 0; r < RPL; r++) {
        int gi = row0 + r;
        bool ok = cok && gi >= 0 && gi < NXY;
        v2f kv = {0.f,0.f}, av = {0.f,0.f}, cv = {0.f,0.f}, pv = {0.f,0.f};
        if (ok) {
            int idx = gi * NXY + gj;
            kv = *(const v2f*)(kg + idx);
            av = *(const v2f*)(ag + idx);
            cv = *(const v2f*)(curg + idx);
            pv = *(const v2f*)(prvg + idx);
        }
        yc[r] = cv; yp[r] = pv; Ka[r] = kv;
        // out-of-domain: K=0,Q=0 -> yn = c = 0 forever
        Qa[r] = ok ? (v2f){1.f - 2.f * av.x, 1.f - 2.f * av.y} : (v2f){0.f, 0.f};
    }

    // source (40,96): even column in all owning tiles (bj=1: lane 32, bj=2: lane 0)
    int sr = 40 - I0, sc = 96 - J0;
    bool wave_src = (sc >= 0 && sc < 128) && (sr >= RPL * w) && (sr < RPL * w + RPL);
    int src_rl = sr - RPL * w;
    float srcm = (2 * l == sc) ? 1.f : 0.f;

    // probe: row 160 (bi==10, wave 3, local r=2), col 48*(bj+1) -> even lane
    bool blk_prb = (bi == 10);
    int pr = 160 - I0;
    bool wave_prb = blk_prb && (pr >= RPL * w) && (pr < RPL * w + RPL);
    int prb_rl = pr - RPL * w;
    float prbm = (2 * l == (48 * (bj + 1) - J0)) ? 1.f : 0.f;
    float pacc = 0.f;

    v2f uph, dnh;

// row update: yn = c + Q*(p-c) + K*(S-4c)  — packed fp32 (v_pk_add/v_pk_fma)
#define ROWC(CUR, PRV, rr_, UP, DN, YN) do {                                   \
    v2f cv = CUR[rr_];                                                         \
    float lf0 = dpp_up1(cv.y);                                                 \
    float rt1 = dpp_dn1(cv.x);                                                 \
    v2f h = (v2f){lf0, rt1} + __builtin_shufflevector(cv, cv, 1, 0);           \
    v2f S = ((UP) + (DN)) + h;                                                 \
    YN = cv + Qa[rr_] * (PRV[rr_] - cv) + Ka[rr_] * (S - 4.0f * cv);           \
    if (wave_src && (rr_) == src_rl) YN.x += srcm * xsv;                       \
    if (wave_prb && (rr_) == prb_rl) { float tq = prbm * YN.x; pacc += tq * YN.x; } \
} while (0)

// boundary rows first (early LDS write), interior hides it; halo read after
// barrier is first used next step
#define STEP(CUR, PRV, PH, SIDX) do {                                          \
    float xsv = xs_l[SIDX];                                                    \
    v2f t0, t9;                                                                \
    ROWC(CUR, PRV, 0, uph,    CUR[1], t0);                                     \
    ROWC(CUR, PRV, 9, CUR[8], dnh,    t9);                                     \
    hb[PH][0][w + 1][l] = t0;                                                  \
    hb[PH][1][w + 1][l] = t9;                                                  \
    PRV[0] = t0; PRV[9] = t9;                                                  \
    _Pragma("unroll")                                                          \
    for (int r = 1; r <= 8; r++) {                                             \
        v2f y;                                                                 \
        ROWC(CUR, PRV, r, CUR[r - 1], CUR[r + 1], y);                          \
        PRV[r] = y;                                                            \
    }                                                                          \
    __syncthreads();                                                           \
    uph = hb[PH][1][w][l];                                                     \
    dnh = hb[PH][0][w + 2][l];                                                 \
} while (0)

    // prologue halo exchange (parity 0)
    hb[0][0][w + 1][l] = yc[0];
    hb[0][1][w + 1][l] = yc[9];
    __syncthreads();
    uph = hb[0][1][w][l];
    dnh = hb[0][0][w + 2][l];

#pragma unroll 1
    for (int s2 = 0; s2 < TCH / 2; s2++) {
        STEP(yc, yp, 1, 2 * s2);        // new cur -> yp, writes hb[1]
        STEP(yp, yc, 0, 2 * s2 + 1);    // new cur -> yc, writes hb[0]
    }
#undef STEP
#undef ROWC
    // yc = y(t_end), yp = y(t_end - 1)

    // store out-tile: rows [16bi,16bi+16), cols lanes 16..47
#pragma unroll
    for (int r = 0; r < RPL; r++) {
        int gi = row0 + r;
        if (gi >= 16 * bi && gi < 16 * bi + 16 && l >= 16 && l < 48) {
            int idx = gi * NXY + gj;
            *(v2f*)(ncurg + idx) = yc[r];
            *(v2f*)(nprvg + idx) = yp[r];
        }
    }
    if (wave_prb && prbm == 1.f) ws[I_OFF + b * 3 + bj] += pacc;
}

__global__ void final_k(const float* __restrict__ ws, float* __restrict__ out) {
    int t = threadIdx.x;
    if (t < 12) {
        const float* I = ws + I_OFF;
        int b = t / 3;
        float s = I[3 * b] + I[3 * b + 1] + I[3 * b + 2];
        out[t] = I[t] / s;
    }
}

extern "C" void kernel_launch(void* const* d_in, const int* in_sizes, int n_in,
                              void* d_out, int out_size, void* d_ws, size_t ws_size,
                              hipStream_t stream) {
    const float* x   = (const float*)d_in[0];   // (4,256) fp32
    const float* rho = (const float*)d_in[1];   // (192,192) fp32
    float* ws  = (float*)d_ws;
    float* out = (float*)d_out;

    setup_k<<<256, 256, 0, stream>>>(rho, ws);
    for (int c = 0; c < NCHUNK; c++)
        chunk_k<<<NBLKS, TPB, 0, stream>>>(x, ws, c);
    final_k<<<1, 64, 0, stream>>>(ws, out);
}